// Round 6
// baseline (578.080 us; speedup 1.0000x reference)
//
#include <hip/hip_runtime.h>
#include <math.h>

// ---------------------------------------------------------------------------
// B=4, S=8192, D=1024, H=4, hd=256.
// Lattice positions {12,36,104,304,888,2592,7568}; 16 entries level-major
// (L1 rows 0..27, L2 rows 28..51, L3 rows 52..63; row = e*4+b).
//
// 7 kernels, stream-ordered. Each kernel's surplus blocks copy a static
// slice of x->out (plain loads, nontemporal stores, skip the 28 rows).
// GEMMs: one block per 8 output columns => each weight j-slice fetched by
// exactly ONE block (weights ~56 MB unique traffic total). Waves own 2
// columns x ALL rows (compile-time row sets via templates).
// ---------------------------------------------------------------------------

#define SEQ 8192
#define DM  1024

typedef float fx4 __attribute__((ext_vector_type(4)));

// ---- compile-time tables (folded into code by templates) -------------------
constexpr int   TN[16][3] = {
  {0,2,4},{2,4,12},{4,12,36},{12,36,104},{36,104,304},{104,304,888},{304,888,2592},
  {0,0,0},{0,2,0},{0,2,4},{2,4,12},{4,12,36},{12,36,104},
  {0,0,0},{0,2,0},{0,2,4}};
constexpr float TW[16][3] = {
  {1,1,1},{1,1,1},{1,1,1},{1,1,1},{1,1,1},{1,1,1},{1,1,1},
  {1,0,0},{1,1,0},{1,1,1},{1,2,3},{1,2,3},{1,2,3},
  {1,0,0},{1,1,0},{1,1,1}};
constexpr float TWI[16] = {
  1.f/3.f,1.f/3.f,1.f/3.f,1.f/3.f,1.f/3.f,1.f/3.f,1.f/3.f,
  1.f,0.5f,1.f/3.f,1.f/6.f,1.f/6.f,1.f/6.f,
  1.f,0.5f,1.f/3.f};
constexpr int TPOS[7] = {12,36,104,304,888,2592,7568};

// runtime-indexed copies for k_attn
__device__ __constant__ int c_pos[7]  = {12,36,104,304,888,2592,7568};
__device__ __constant__ int c_ne[7]   = {1,2,2,2,3,3,3};
__device__ __constant__ int c_posE[7][3] = {
  {0,0,0},{1,7,0},{2,8,0},{3,9,0},{4,10,13},{5,11,14},{6,12,15}};

// ---------------------------------------------------------------------------
// copy 2 chunks (16 KB each = 4 rows) at c0; loads unconditional (8 in
// flight), stores skip the 28 chain-written rows.
// ---------------------------------------------------------------------------
__device__ __forceinline__ void copy2(const float* __restrict__ x,
                                      float* __restrict__ out, int c0)
{
  const fx4* __restrict__ src4 = (const fx4*)x;
  fx4* __restrict__ dst4 = (fx4*)out;
  const int tid = threadIdx.x;
  fx4 v[8]; size_t idx[8]; int row[8];
#pragma unroll
  for (int u = 0; u < 8; ++u) {
    const int c = c0 + (u >> 2), k = u & 3;
    idx[u] = (size_t)c * 1024 + (size_t)k * 256 + tid;
    row[u] = (c * 4 + k) & (SEQ - 1);
    v[u] = src4[idx[u]];
  }
#pragma unroll
  for (int u = 0; u < 8; ++u) {
    const int s = row[u];
    if (s==12 || s==36 || s==104 || s==304 || s==888 || s==2592 || s==7568)
      continue;
    __builtin_nontemporal_store(v[u], &dst4[idx[u]]);
  }
}

// ---------------------------------------------------------------------------
// GEMM skeleton: wave wv owns columns j0=jt*8+wv*2, j0+1; lanes over k.
// ---------------------------------------------------------------------------
template<int NR, int T, class F>
__device__ __forceinline__ void gemm_acc(float (&A0)[NR], float (&A1)[NR],
                                         const F& src,
                                         const float* __restrict__ W,
                                         int Wld, int wcol0, int j0)
{
  const int lane = threadIdx.x & 63;
#pragma unroll
  for (int t = 0; t < T; ++t) {
    const int kx = t * 256 + lane * 4;
    const float4 w0 = *(const float4*)(W + (size_t)j0 * Wld + wcol0 + kx);
    const float4 w1 = *(const float4*)(W + (size_t)(j0+1) * Wld + wcol0 + kx);
#pragma unroll
    for (int r = 0; r < NR; ++r) {
      const float4 xv = src(r, kx);
      A0[r] += w0.x*xv.x + w0.y*xv.y + w0.z*xv.z + w0.w*xv.w;
      A1[r] += w1.x*xv.x + w1.y*xv.y + w1.z*xv.z + w1.w*xv.w;
    }
  }
}

template<int NR>
__device__ __forceinline__ void gemm_fin(float (&A0)[NR], float (&A1)[NR],
                                         const float* __restrict__ Bv, int j0,
                                         float* __restrict__ Y, int ldy, int r0)
{
  const int lane = threadIdx.x & 63;
#pragma unroll
  for (int r = 0; r < NR; ++r) {
    float a = A0[r], b = A1[r];
#pragma unroll
    for (int off = 32; off >= 1; off >>= 1) {
      a += __shfl_xor(a, off); b += __shfl_xor(b, off);
    }
    if (lane == 0) {
      float* yr = Y + (size_t)(r0 + r) * ldy + j0;
      yr[0] = a + Bv[j0]; yr[1] = b + Bv[j0 + 1];
    }
  }
}

// ---- row sources -----------------------------------------------------------
// F rows on the fly (weighted mean of up to 3 x-rows; all indices folded)
template<int R0>
struct SrcF {
  const float* __restrict__ x;
  __device__ __forceinline__ float4 operator()(int r, int kx) const {
    const int gr = R0 + r, e = gr >> 2, b = gr & 3;
    float sx = 0.f, sy = 0.f, sz = 0.f, sw = 0.f;
#pragma unroll
    for (int n = 0; n < 3; ++n) {
      const float w = TW[e][n];
      if (w != 0.f) {
        const float4 v = *(const float4*)(x + ((size_t)b*SEQ + TN[e][n])*DM + kx);
        sx += w*v.x; sy += w*v.y; sz += w*v.z; sw += w*v.w;
      }
    }
    const float wi = TWI[e];
    return make_float4(sx*wi, sy*wi, sz*wi, sw*wi);
  }
};

// LN+GELU(H) rows on the fly (stats from LDS)
template<int R0>
struct SrcG {
  const float* __restrict__ H;
  const float* __restrict__ g;
  const float* __restrict__ bt;
  const float (*st)[2];
  __device__ __forceinline__ float4 operator()(int r, int kx) const {
    const float4 h  = *(const float4*)(H + (size_t)(R0 + r)*DM + kx);
    const float4 gv = *(const float4*)(g + kx);
    const float4 bv = *(const float4*)(bt + kx);
    const float m = st[r][0], rs = st[r][1];
    const float t0 = (h.x-m)*rs*gv.x + bv.x;
    const float t1 = (h.y-m)*rs*gv.y + bv.y;
    const float t2 = (h.z-m)*rs*gv.z + bv.z;
    const float t3 = (h.w-m)*rs*gv.w + bv.w;
    const float kc = 0.70710678118654752f;
    return make_float4(0.5f*t0*(1.f+erff(t0*kc)), 0.5f*t1*(1.f+erff(t1*kc)),
                      0.5f*t2*(1.f+erff(t2*kc)), 0.5f*t3*(1.f+erff(t3*kc)));
  }
};

// the 28 q-rows of x (row r = p*4+b)
struct SrcQ {
  const float* __restrict__ x;
  __device__ __forceinline__ float4 operator()(int r, int kx) const {
    const int p = r >> 2, b = r & 3;
    return *(const float4*)(x + ((size_t)b*SEQ + TPOS[p])*DM + kx);
  }
};

// plain contiguous rows
struct SrcR {
  const float* __restrict__ base;
  __device__ __forceinline__ float4 operator()(int r, int kx) const {
    return *(const float4*)(base + (size_t)r*DM + kx);
  }
};

// ---------------------------------------------------------------------------
// K1: H = F @ lt_w1^T + b1   (384 gemm blocks: lvl(3) x jt(128))
// ---------------------------------------------------------------------------
template<int LVL, int NR, int R0>
__device__ __forceinline__ void lat1_block(const float* x, const float* w1,
                                           const float* b1, float* Hh, int jt)
{
  const int j0 = jt*8 + (threadIdx.x >> 6)*2;
  float A0[NR], A1[NR];
#pragma unroll
  for (int r = 0; r < NR; ++r) { A0[r]=0.f; A1[r]=0.f; }
  SrcF<R0> src{x};
  gemm_acc<NR,4>(A0, A1, src, w1 + (size_t)LVL*DM*DM, DM, 0, j0);
  gemm_fin<NR>(A0, A1, b1 + LVL*DM, j0, Hh, DM, R0);
}

__global__ __launch_bounds__(256)
void k_lat1(const float* __restrict__ x, const float* __restrict__ w1,
            const float* __restrict__ b1, float* __restrict__ Hh,
            float* __restrict__ out)
{
  const int bid = blockIdx.x;
  if (bid >= 384) { copy2(x, out, (bid - 384) * 2); return; }
  const int lvl = bid >> 7, jt = bid & 127;
  if (lvl == 0)      lat1_block<0,28, 0>(x, w1, b1, Hh, jt);
  else if (lvl == 1) lat1_block<1,24,28>(x, w1, b1, Hh, jt);
  else               lat1_block<2,12,52>(x, w1, b1, Hh, jt);
}

// ---------------------------------------------------------------------------
// K2: KV = LN+GELU(H) @ lt_w2^T + b2  (384 gemm blocks)
// ---------------------------------------------------------------------------
template<int LVL, int NR, int R0>
__device__ __forceinline__ void lat2_block(const float* H, const float* lng,
                                           const float* lnb, const float* w2,
                                           const float* b2, float* KV, int jt,
                                           float (*st)[2])
{
  const int lane = threadIdx.x & 63, wv = threadIdx.x >> 6;
  // stats prepass: wave wv handles rows wv, wv+4, ...
  for (int r = wv; r < NR; r += 4) {
    const int gr = R0 + r;
    float s = 0.f, q = 0.f;
#pragma unroll
    for (int u = 0; u < 4; ++u) {
      const float4 h = *(const float4*)(H + (size_t)gr*DM + (lane + u*64)*4);
      s += h.x+h.y+h.z+h.w;
      q += h.x*h.x+h.y*h.y+h.z*h.z+h.w*h.w;
    }
#pragma unroll
    for (int off = 32; off >= 1; off >>= 1) {
      s += __shfl_xor(s, off); q += __shfl_xor(q, off);
    }
    if (lane == 0) {
      const float m = s * (1.f/1024.f);
      st[r][0] = m;
      st[r][1] = rsqrtf(q * (1.f/1024.f) - m*m + 1e-5f);
    }
  }
  __syncthreads();
  const int j0 = jt*8 + wv*2;
  float A0[NR], A1[NR];
#pragma unroll
  for (int r = 0; r < NR; ++r) { A0[r]=0.f; A1[r]=0.f; }
  SrcG<R0> src{H, lng + LVL*DM, lnb + LVL*DM, (const float(*)[2])st};
  gemm_acc<NR,4>(A0, A1, src, w2 + (size_t)LVL*DM*DM, DM, 0, j0);
  gemm_fin<NR>(A0, A1, b2 + LVL*DM, j0, KV, DM, R0);
}

__global__ __launch_bounds__(256)
void k_lat2(const float* __restrict__ x, const float* __restrict__ Hh,
            const float* __restrict__ lng, const float* __restrict__ lnb,
            const float* __restrict__ w2, const float* __restrict__ b2,
            float* __restrict__ KV, float* __restrict__ out)
{
  __shared__ float st[32][2];
  const int bid = blockIdx.x;
  if (bid >= 384) { copy2(x, out, 1170 + (bid - 384) * 2); return; }
  const int lvl = bid >> 7, jt = bid & 127;
  if (lvl == 0)      lat2_block<0,28, 0>(Hh, lng, lnb, w2, b2, KV, jt, st);
  else if (lvl == 1) lat2_block<1,24,28>(Hh, lng, lnb, w2, b2, KV, jt, st);
  else               lat2_block<2,12,52>(Hh, lng, lnb, w2, b2, KV, jt, st);
}

// ---------------------------------------------------------------------------
// K3: Q/K/V projections. Q: 128 blocks (28 x-rows); K,V: 256 blocks each
// (row halves of KV). 640 gemm blocks total.
// ---------------------------------------------------------------------------
__global__ __launch_bounds__(256)
void k_qkv(const float* __restrict__ x, const float* __restrict__ KV,
           const float* __restrict__ Wi, const float* __restrict__ Bi,
           float* __restrict__ QH, float* __restrict__ KH,
           float* __restrict__ VH, float* __restrict__ out)
{
  const int bid = blockIdx.x;
  if (bid >= 640) { copy2(x, out, 2340 + (bid - 640) * 2); return; }
  const int wv = threadIdx.x >> 6;
  if (bid < 128) {
    const int j0 = bid*8 + wv*2;
    float A0[28], A1[28];
#pragma unroll
    for (int r = 0; r < 28; ++r) { A0[r]=0.f; A1[r]=0.f; }
    SrcQ src{x};
    gemm_acc<28,4>(A0, A1, src, Wi, DM, 0, j0);
    gemm_fin<28>(A0, A1, Bi, j0, QH, DM, 0);
  } else {
    const int i = bid - 128;            // 0..511 : [K|V] x rh x jt
    const int mat = i >> 8;             // 0=K, 1=V
    const int rh = (i >> 7) & 1, jt = i & 127;
    const int j0 = jt*8 + wv*2;
    float A0[32], A1[32];
#pragma unroll
    for (int r = 0; r < 32; ++r) { A0[r]=0.f; A1[r]=0.f; }
    SrcR src{KV + (size_t)rh*32*DM};
    const float* W = Wi + (size_t)(mat+1)*DM*DM;
    gemm_acc<32,4>(A0, A1, src, W, DM, 0, j0);
    gemm_fin<32>(A0, A1, Bi + (mat+1)*DM, j0, mat ? VH : KH, DM, rh*32);
  }
}

// ---------------------------------------------------------------------------
// K4: attention. Block=(p,b), wave=head.
// ---------------------------------------------------------------------------
__global__ __launch_bounds__(256)
void k_attn(const float* __restrict__ x, const float* __restrict__ QH,
            const float* __restrict__ KH, const float* __restrict__ VH,
            float* __restrict__ OA, float* __restrict__ out)
{
  const int bid = blockIdx.x;
  if (bid >= 28) { copy2(x, out, 3510 + (bid - 28) * 2); return; }
  const int p = bid >> 2, b = bid & 3;
  const int h = threadIdx.x >> 6, lane = threadIdx.x & 63;
  const int ne = c_ne[p];
  const int qoff = (p*4+b)*DM + h*256 + lane;
  const float q0 = QH[qoff], q1 = QH[qoff+64], q2 = QH[qoff+128], q3 = QH[qoff+192];
  float sc0 = -1e30f, sc1 = -1e30f, sc2 = -1e30f;
  int k0 = 0, k1 = 0, k2 = 0;
  {
    k0 = (c_posE[p][0]*4 + b)*DM + h*256 + lane;
    float pr = q0*KH[k0] + q1*KH[k0+64] + q2*KH[k0+128] + q3*KH[k0+192];
#pragma unroll
    for (int off = 32; off >= 1; off >>= 1) pr += __shfl_xor(pr, off);
    sc0 = pr * 0.0625f;
  }
  if (ne > 1) {
    k1 = (c_posE[p][1]*4 + b)*DM + h*256 + lane;
    float pr = q0*KH[k1] + q1*KH[k1+64] + q2*KH[k1+128] + q3*KH[k1+192];
#pragma unroll
    for (int off = 32; off >= 1; off >>= 1) pr += __shfl_xor(pr, off);
    sc1 = pr * 0.0625f;
  }
  if (ne > 2) {
    k2 = (c_posE[p][2]*4 + b)*DM + h*256 + lane;
    float pr = q0*KH[k2] + q1*KH[k2+64] + q2*KH[k2+128] + q3*KH[k2+192];
#pragma unroll
    for (int off = 32; off >= 1; off >>= 1) pr += __shfl_xor(pr, off);
    sc2 = pr * 0.0625f;
  }
  const float m = fmaxf(sc0, fmaxf(sc1, sc2));
  const float e0 = expf(sc0 - m);
  const float e1 = (ne > 1) ? expf(sc1 - m) : 0.f;
  const float e2 = (ne > 2) ? expf(sc2 - m) : 0.f;
  const float inv = 1.f / (e0 + e1 + e2);
  const float A0 = e0*inv, A1 = e1*inv, A2 = e2*inv;
#pragma unroll
  for (int i = 0; i < 4; ++i) {
    float o = A0 * VH[k0 + i*64];
    if (ne > 1) o += A1 * VH[k1 + i*64];
    if (ne > 2) o += A2 * VH[k2 + i*64];
    OA[qoff + i*64] = o;
  }
}

// ---------------------------------------------------------------------------
// K5: O = OA @ attn_out_w^T + b   (128 gemm blocks)
// ---------------------------------------------------------------------------
__global__ __launch_bounds__(256)
void k_oproj(const float* __restrict__ x, const float* __restrict__ OA,
             const float* __restrict__ Wo, const float* __restrict__ Bo,
             float* __restrict__ O, float* __restrict__ out)
{
  const int bid = blockIdx.x;
  if (bid >= 128) { copy2(x, out, 4910 + (bid - 128) * 2); return; }
  const int j0 = bid*8 + (threadIdx.x >> 6)*2;
  float A0[28], A1[28];
#pragma unroll
  for (int r = 0; r < 28; ++r) { A0[r]=0.f; A1[r]=0.f; }
  SrcR src{OA};
  gemm_acc<28,4>(A0, A1, src, Wo, DM, 0, j0);
  gemm_fin<28>(A0, A1, Bo, j0, O, DM, 0);
}

// ---------------------------------------------------------------------------
// K6: UP = [O | x-rows] @ fus_w^T + b   (K=2048; 128 gemm blocks)
// ---------------------------------------------------------------------------
__global__ __launch_bounds__(256)
void k_fus(const float* __restrict__ x, const float* __restrict__ O,
           const float* __restrict__ Wf, const float* __restrict__ Bf,
           float* __restrict__ UP, float* __restrict__ out)
{
  const int bid = blockIdx.x;
  if (bid >= 128) { copy2(x, out, 6080 + (bid - 128) * 2); return; }
  const int j0 = bid*8 + (threadIdx.x >> 6)*2;
  float A0[28], A1[28];
#pragma unroll
  for (int r = 0; r < 28; ++r) { A0[r]=0.f; A1[r]=0.f; }
  SrcR srcO{O};
  gemm_acc<28,4>(A0, A1, srcO, Wf, 2048, 0, j0);
  SrcQ srcX{x};
  gemm_acc<28,4>(A0, A1, srcX, Wf, 2048, 1024, j0);
  gemm_fin<28>(A0, A1, Bf, j0, UP, DM, 0);
}

// ---------------------------------------------------------------------------
// K7: final LN + scatter the 28 rows
// ---------------------------------------------------------------------------
__global__ __launch_bounds__(256)
void k_final(const float* __restrict__ x, const float* __restrict__ UP,
             const float* __restrict__ g, const float* __restrict__ bt,
             float* __restrict__ out)
{
  __shared__ float s1[4], s2[4];
  const int bid = blockIdx.x;
  if (bid >= 28) { copy2(x, out, 7250 + (bid - 28) * 2); return; }
  const int p = bid >> 2, b = bid & 3;
  const int j = threadIdx.x * 4;
  const int lane = threadIdx.x & 63, wv = threadIdx.x >> 6;
  const float4 v = *(const float4*)(UP + (size_t)bid*DM + j);
  float s = v.x+v.y+v.z+v.w;
  float q = v.x*v.x+v.y*v.y+v.z*v.z+v.w*v.w;
#pragma unroll
  for (int off = 32; off >= 1; off >>= 1) {
    s += __shfl_xor(s, off); q += __shfl_xor(q, off);
  }
  if (lane == 0) { s1[wv] = s; s2[wv] = q; }
  __syncthreads();
  const float ts = s1[0]+s1[1]+s1[2]+s1[3];
  const float tq = s2[0]+s2[1]+s2[2]+s2[3];
  const float m = ts * (1.f/1024.f);
  const float rs = rsqrtf(tq * (1.f/1024.f) - m*m + 1e-5f);
  const float* gg = g + j;
  const float* bb = bt + j;
  float4 o;
  o.x = (v.x-m)*rs*gg[0] + bb[0];
  o.y = (v.y-m)*rs*gg[1] + bb[1];
  o.z = (v.z-m)*rs*gg[2] + bb[2];
  o.w = (v.w-m)*rs*gg[3] + bb[3];
  *(float4*)(out + ((size_t)b*SEQ + c_pos[p])*DM + j) = o;
}

// ---------------------------------------------------------------------------
// Launch: grids = gemm blocks + copy blocks (2 chunks each)
// chunk ranges: lat1 [0,1170) lat2 [1170,2340) qkv [2340,3510)
// attn [3510,4910) oproj [4910,6080) fus [6080,7250) final [7250,8192)
// ---------------------------------------------------------------------------
extern "C" void kernel_launch(void* const* d_in, const int* in_sizes, int n_in,
                              void* d_out, int out_size, void* d_ws, size_t ws_size,
                              hipStream_t stream)
{
  const float* x          = (const float*)d_in[0];
  const float* lt_w1      = (const float*)d_in[1];
  const float* lt_b1      = (const float*)d_in[2];
  const float* lt_ln_g    = (const float*)d_in[3];
  const float* lt_ln_b    = (const float*)d_in[4];
  const float* lt_w2      = (const float*)d_in[5];
  const float* lt_b2      = (const float*)d_in[6];
  const float* attn_in_w  = (const float*)d_in[7];
  const float* attn_in_b  = (const float*)d_in[8];
  const float* attn_out_w = (const float*)d_in[9];
  const float* attn_out_b = (const float*)d_in[10];
  const float* fus_w      = (const float*)d_in[11];
  const float* fus_b      = (const float*)d_in[12];
  const float* fus_ln_g   = (const float*)d_in[13];
  const float* fus_ln_b   = (const float*)d_in[14];
  float* out = (float*)d_out;
  float* ws  = (float*)d_ws;

  float* Hh = ws;                  // 64 x 1024
  float* KV = Hh + 65536;          // 64 x 1024
  float* QH = KV + 65536;          // 28 x 1024 (32 alloc)
  float* KH = QH + 32768;          // 64 x 1024
  float* VH = KH + 65536;          // 64 x 1024
  float* OA = VH + 65536;          // 28 x 1024
  float* O  = OA + 32768;          // 28 x 1024
  float* UP = O  + 32768;          // 28 x 1024

  k_lat1 <<<969,  256, 0, stream>>>(x, lt_w1, lt_b1, Hh, out);
  k_lat2 <<<969,  256, 0, stream>>>(x, Hh, lt_ln_g, lt_ln_b, lt_w2, lt_b2, KV, out);
  k_qkv  <<<1225, 256, 0, stream>>>(x, KV, attn_in_w, attn_in_b, QH, KH, VH, out);
  k_attn <<<728,  256, 0, stream>>>(x, QH, KH, VH, OA, out);
  k_oproj<<<713,  256, 0, stream>>>(x, OA, attn_out_w, attn_out_b, O, out);
  k_fus  <<<713,  256, 0, stream>>>(x, O, fus_w, fus_b, UP, out);
  k_final<<<499,  256, 0, stream>>>(x, UP, fus_ln_g, fus_ln_b, out);
}

// Round 7
// 248.012 us; speedup vs baseline: 2.3309x; 2.3309x over previous
//
#include <hip/hip_runtime.h>
#include <math.h>

// ---------------------------------------------------------------------------
// B=4, S=8192, D=1024, H=4, hd=256.
// Lattice positions {12,36,104,304,888,2592,7568}; 16 entries level-major
// (L1 rows 0..27, L2 rows 28..51, L3 rows 52..63; row = e*4+b).
//
// 8 kernels, stream-ordered. Each kernel's surplus blocks copy a static
// slice of x->out (plain loads keep x L3-resident, nontemporal stores,
// skip the 28 chain-written rows; 4 chunks / 16 loads in flight per block).
// GEMMs: one block per 8 output columns => each weight j-slice fetched by
// exactly ONE block. Waves own 2 columns x ALL rows (compile-time row sets).
// LN+GELU isolated in k_ln (erf in a GEMM functor spills — round-6 lesson).
// ---------------------------------------------------------------------------

#define SEQ 8192
#define DM  1024

typedef float fx4 __attribute__((ext_vector_type(4)));

// ---- compile-time tables ---------------------------------------------------
constexpr int   TN[16][3] = {
  {0,2,4},{2,4,12},{4,12,36},{12,36,104},{36,104,304},{104,304,888},{304,888,2592},
  {0,0,0},{0,2,0},{0,2,4},{2,4,12},{4,12,36},{12,36,104},
  {0,0,0},{0,2,0},{0,2,4}};
constexpr float TW[16][3] = {
  {1,1,1},{1,1,1},{1,1,1},{1,1,1},{1,1,1},{1,1,1},{1,1,1},
  {1,0,0},{1,1,0},{1,1,1},{1,2,3},{1,2,3},{1,2,3},
  {1,0,0},{1,1,0},{1,1,1}};
constexpr float TWI[16] = {
  1.f/3.f,1.f/3.f,1.f/3.f,1.f/3.f,1.f/3.f,1.f/3.f,1.f/3.f,
  1.f,0.5f,1.f/3.f,1.f/6.f,1.f/6.f,1.f/6.f,
  1.f,0.5f,1.f/3.f};
constexpr int TPOS[7] = {12,36,104,304,888,2592,7568};

__device__ __constant__ int c_pos[7]  = {12,36,104,304,888,2592,7568};
__device__ __constant__ int c_ne[7]   = {1,2,2,2,3,3,3};
__device__ __constant__ int c_posE[7][3] = {
  {0,0,0},{1,7,0},{2,8,0},{3,9,0},{4,10,13},{5,11,14},{6,12,15}};

// ---------------------------------------------------------------------------
// copy 4 chunks (16 KB each = 4 rows) at c0; 16 loads in flight, stores
// skip the 28 chain-written rows.
// ---------------------------------------------------------------------------
__device__ __forceinline__ void copy4(const float* __restrict__ x,
                                      float* __restrict__ out, int c0)
{
  const fx4* __restrict__ src4 = (const fx4*)x;
  fx4* __restrict__ dst4 = (fx4*)out;
  const int tid = threadIdx.x;
  fx4 v[16]; size_t idx[16];
#pragma unroll
  for (int u = 0; u < 16; ++u) {
    const int c = c0 + (u >> 2), k = u & 3;
    idx[u] = (size_t)c * 1024 + (size_t)k * 256 + tid;
    v[u] = src4[idx[u]];
  }
#pragma unroll
  for (int u = 0; u < 16; ++u) {
    const int s = ((c0 + (u >> 2)) * 4 + (u & 3)) & (SEQ - 1);
    if (s==12 || s==36 || s==104 || s==304 || s==888 || s==2592 || s==7568)
      continue;
    __builtin_nontemporal_store(v[u], &dst4[idx[u]]);
  }
}

// ---------------------------------------------------------------------------
// GEMM skeleton: wave wv owns columns j0, j0+1; lanes over k (float4).
// ---------------------------------------------------------------------------
template<int NR, int T, class F>
__device__ __forceinline__ void gemm_acc(float (&A0)[NR], float (&A1)[NR],
                                         const F& src,
                                         const float* __restrict__ W,
                                         int Wld, int wcol0, int j0)
{
  const int lane = threadIdx.x & 63;
#pragma unroll
  for (int t = 0; t < T; ++t) {
    const int kx = t * 256 + lane * 4;
    const float4 w0 = *(const float4*)(W + (size_t)j0 * Wld + wcol0 + kx);
    const float4 w1 = *(const float4*)(W + (size_t)(j0+1) * Wld + wcol0 + kx);
#pragma unroll
    for (int r = 0; r < NR; ++r) {
      const float4 xv = src(r, kx);
      A0[r] += w0.x*xv.x + w0.y*xv.y + w0.z*xv.z + w0.w*xv.w;
      A1[r] += w1.x*xv.x + w1.y*xv.y + w1.z*xv.z + w1.w*xv.w;
    }
  }
}

template<int NR>
__device__ __forceinline__ void gemm_fin(float (&A0)[NR], float (&A1)[NR],
                                         const float* __restrict__ Bv, int j0,
                                         float* __restrict__ Y, int ldy, int r0)
{
  const int lane = threadIdx.x & 63;
#pragma unroll
  for (int r = 0; r < NR; ++r) {
    float a = A0[r], b = A1[r];
#pragma unroll
    for (int off = 32; off >= 1; off >>= 1) {
      a += __shfl_xor(a, off); b += __shfl_xor(b, off);
    }
    if (lane == 0) {
      float* yr = Y + (size_t)(r0 + r) * ldy + j0;
      yr[0] = a + Bv[j0]; yr[1] = b + Bv[j0 + 1];
    }
  }
}

// ---- row sources -----------------------------------------------------------
template<int R0>
struct SrcF {               // F rows on the fly (weighted mean of <=3 x-rows)
  const float* __restrict__ x;
  __device__ __forceinline__ float4 operator()(int r, int kx) const {
    const int gr = R0 + r, e = gr >> 2, b = gr & 3;
    float sx = 0.f, sy = 0.f, sz = 0.f, sw = 0.f;
#pragma unroll
    for (int n = 0; n < 3; ++n) {
      const float w = TW[e][n];
      if (w != 0.f) {
        const float4 v = *(const float4*)(x + ((size_t)b*SEQ + TN[e][n])*DM + kx);
        sx += w*v.x; sy += w*v.y; sz += w*v.z; sw += w*v.w;
      }
    }
    const float wi = TWI[e];
    return make_float4(sx*wi, sy*wi, sz*wi, sw*wi);
  }
};

struct SrcQ {               // the 28 q-rows of x (row r = p*4+b)
  const float* __restrict__ x;
  __device__ __forceinline__ float4 operator()(int r, int kx) const {
    const int p = r >> 2, b = r & 3;
    return *(const float4*)(x + ((size_t)b*SEQ + TPOS[p])*DM + kx);
  }
};

struct SrcR {               // plain contiguous rows
  const float* __restrict__ base;
  __device__ __forceinline__ float4 operator()(int r, int kx) const {
    return *(const float4*)(base + (size_t)r*DM + kx);
  }
};

// ---------------------------------------------------------------------------
// K1: H = F @ lt_w1^T + b1   (384 gemm blocks; copy chunks [0,1000))
// ---------------------------------------------------------------------------
template<int LVL, int NR, int R0>
__device__ __forceinline__ void lat1_block(const float* x, const float* w1,
                                           const float* b1, float* Hh, int jt)
{
  const int j0 = jt*8 + (threadIdx.x >> 6)*2;
  float A0[NR], A1[NR];
#pragma unroll
  for (int r = 0; r < NR; ++r) { A0[r]=0.f; A1[r]=0.f; }
  SrcF<R0> src{x};
  gemm_acc<NR,4>(A0, A1, src, w1 + (size_t)LVL*DM*DM, DM, 0, j0);
  gemm_fin<NR>(A0, A1, b1 + LVL*DM, j0, Hh, DM, R0);
}

__global__ __launch_bounds__(256)
void k_lat1(const float* __restrict__ x, const float* __restrict__ w1,
            const float* __restrict__ b1, float* __restrict__ Hh,
            float* __restrict__ out)
{
  const int bid = blockIdx.x;
  if (bid >= 384) { copy4(x, out, (bid - 384) * 4); return; }
  const int lvl = bid >> 7, jt = bid & 127;
  if (lvl == 0)      lat1_block<0,28, 0>(x, w1, b1, Hh, jt);
  else if (lvl == 1) lat1_block<1,24,28>(x, w1, b1, Hh, jt);
  else               lat1_block<2,12,52>(x, w1, b1, Hh, jt);
}

// ---------------------------------------------------------------------------
// K2: G = GELU(LN(H))  (64 blocks, one row each; copy chunks [1000,2200))
// ---------------------------------------------------------------------------
__global__ __launch_bounds__(256)
void k_ln(const float* __restrict__ x, const float* __restrict__ Hh,
          const float* __restrict__ lng, const float* __restrict__ lnb,
          float* __restrict__ G, float* __restrict__ out)
{
  __shared__ float s1[4], s2[4];
  const int bid = blockIdx.x;
  if (bid >= 64) { copy4(x, out, 1000 + (bid - 64) * 4); return; }
  const int lvl = (bid < 28) ? 0 : ((bid < 52) ? 1 : 2);
  const int j = threadIdx.x * 4;
  const int lane = threadIdx.x & 63, wv = threadIdx.x >> 6;
  const float4 v = *(const float4*)(Hh + (size_t)bid*DM + j);
  float s = v.x+v.y+v.z+v.w;
  float q = v.x*v.x+v.y*v.y+v.z*v.z+v.w*v.w;
#pragma unroll
  for (int off = 32; off >= 1; off >>= 1) {
    s += __shfl_xor(s, off); q += __shfl_xor(q, off);
  }
  if (lane == 0) { s1[wv] = s; s2[wv] = q; }
  __syncthreads();
  const float ts = s1[0]+s1[1]+s1[2]+s1[3];
  const float tq = s2[0]+s2[1]+s2[2]+s2[3];
  const float m = ts * (1.f/1024.f);
  const float rs = rsqrtf(tq * (1.f/1024.f) - m*m + 1e-5f);
  const float4 g4 = *(const float4*)(lng + (size_t)lvl*DM + j);
  const float4 b4 = *(const float4*)(lnb + (size_t)lvl*DM + j);
  const float t0 = (v.x-m)*rs*g4.x + b4.x;
  const float t1 = (v.y-m)*rs*g4.y + b4.y;
  const float t2 = (v.z-m)*rs*g4.z + b4.z;
  const float t3 = (v.w-m)*rs*g4.w + b4.w;
  const float kc = 0.70710678118654752f;
  float4 o;
  o.x = 0.5f*t0*(1.f+erff(t0*kc));
  o.y = 0.5f*t1*(1.f+erff(t1*kc));
  o.z = 0.5f*t2*(1.f+erff(t2*kc));
  o.w = 0.5f*t3*(1.f+erff(t3*kc));
  *(float4*)(G + (size_t)bid*DM + j) = o;
}

// ---------------------------------------------------------------------------
// K3: KV = G @ lt_w2^T + b2  (384 gemm blocks; copy chunks [2200,3200))
// ---------------------------------------------------------------------------
template<int LVL, int NR, int R0>
__device__ __forceinline__ void lat2_block(const float* G, const float* w2,
                                           const float* b2, float* KV, int jt)
{
  const int j0 = jt*8 + (threadIdx.x >> 6)*2;
  float A0[NR], A1[NR];
#pragma unroll
  for (int r = 0; r < NR; ++r) { A0[r]=0.f; A1[r]=0.f; }
  SrcR src{G + (size_t)R0*DM};
  gemm_acc<NR,4>(A0, A1, src, w2 + (size_t)LVL*DM*DM, DM, 0, j0);
  gemm_fin<NR>(A0, A1, b2 + LVL*DM, j0, KV, DM, R0);
}

__global__ __launch_bounds__(256)
void k_lat2(const float* __restrict__ x, const float* __restrict__ G,
            const float* __restrict__ w2, const float* __restrict__ b2,
            float* __restrict__ KV, float* __restrict__ out)
{
  const int bid = blockIdx.x;
  if (bid >= 384) { copy4(x, out, 2200 + (bid - 384) * 4); return; }
  const int lvl = bid >> 7, jt = bid & 127;
  if (lvl == 0)      lat2_block<0,28, 0>(G, w2, b2, KV, jt);
  else if (lvl == 1) lat2_block<1,24,28>(G, w2, b2, KV, jt);
  else               lat2_block<2,12,52>(G, w2, b2, KV, jt);
}

// ---------------------------------------------------------------------------
// K4: Q/K/V projections (640 gemm blocks; copy chunks [3200,4200))
// ---------------------------------------------------------------------------
__global__ __launch_bounds__(256)
void k_qkv(const float* __restrict__ x, const float* __restrict__ KV,
           const float* __restrict__ Wi, const float* __restrict__ Bi,
           float* __restrict__ QH, float* __restrict__ KH,
           float* __restrict__ VH, float* __restrict__ out)
{
  const int bid = blockIdx.x;
  if (bid >= 640) { copy4(x, out, 3200 + (bid - 640) * 4); return; }
  const int wv = threadIdx.x >> 6;
  if (bid < 128) {
    const int j0 = bid*8 + wv*2;
    float A0[28], A1[28];
#pragma unroll
    for (int r = 0; r < 28; ++r) { A0[r]=0.f; A1[r]=0.f; }
    SrcQ src{x};
    gemm_acc<28,4>(A0, A1, src, Wi, DM, 0, j0);
    gemm_fin<28>(A0, A1, Bi, j0, QH, DM, 0);
  } else {
    const int i = bid - 128;            // 0..511 : [K|V] x rh x jt
    const int mat = i >> 8;             // 0=K, 1=V
    const int rh = (i >> 7) & 1, jt = i & 127;
    const int j0 = jt*8 + wv*2;
    float A0[32], A1[32];
#pragma unroll
    for (int r = 0; r < 32; ++r) { A0[r]=0.f; A1[r]=0.f; }
    SrcR src{KV + (size_t)rh*32*DM};
    const float* W = Wi + (size_t)(mat+1)*DM*DM;
    gemm_acc<32,4>(A0, A1, src, W, DM, 0, j0);
    gemm_fin<32>(A0, A1, Bi + (mat+1)*DM, j0, mat ? VH : KH, DM, rh*32);
  }
}

// ---------------------------------------------------------------------------
// K5: attention (28 blocks; copy chunks [4200,5500))
// ---------------------------------------------------------------------------
__global__ __launch_bounds__(256)
void k_attn(const float* __restrict__ x, const float* __restrict__ QH,
            const float* __restrict__ KH, const float* __restrict__ VH,
            float* __restrict__ OA, float* __restrict__ out)
{
  const int bid = blockIdx.x;
  if (bid >= 28) { copy4(x, out, 4200 + (bid - 28) * 4); return; }
  const int p = bid >> 2, b = bid & 3;
  const int h = threadIdx.x >> 6, lane = threadIdx.x & 63;
  const int ne = c_ne[p];
  const int qoff = (p*4+b)*DM + h*256 + lane;
  const float q0 = QH[qoff], q1 = QH[qoff+64], q2 = QH[qoff+128], q3 = QH[qoff+192];
  float sc0 = -1e30f, sc1 = -1e30f, sc2 = -1e30f;
  int k0 = 0, k1 = 0, k2 = 0;
  {
    k0 = (c_posE[p][0]*4 + b)*DM + h*256 + lane;
    float pr = q0*KH[k0] + q1*KH[k0+64] + q2*KH[k0+128] + q3*KH[k0+192];
#pragma unroll
    for (int off = 32; off >= 1; off >>= 1) pr += __shfl_xor(pr, off);
    sc0 = pr * 0.0625f;
  }
  if (ne > 1) {
    k1 = (c_posE[p][1]*4 + b)*DM + h*256 + lane;
    float pr = q0*KH[k1] + q1*KH[k1+64] + q2*KH[k1+128] + q3*KH[k1+192];
#pragma unroll
    for (int off = 32; off >= 1; off >>= 1) pr += __shfl_xor(pr, off);
    sc1 = pr * 0.0625f;
  }
  if (ne > 2) {
    k2 = (c_posE[p][2]*4 + b)*DM + h*256 + lane;
    float pr = q0*KH[k2] + q1*KH[k2+64] + q2*KH[k2+128] + q3*KH[k2+192];
#pragma unroll
    for (int off = 32; off >= 1; off >>= 1) pr += __shfl_xor(pr, off);
    sc2 = pr * 0.0625f;
  }
  const float m = fmaxf(sc0, fmaxf(sc1, sc2));
  const float e0 = expf(sc0 - m);
  const float e1 = (ne > 1) ? expf(sc1 - m) : 0.f;
  const float e2 = (ne > 2) ? expf(sc2 - m) : 0.f;
  const float inv = 1.f / (e0 + e1 + e2);
  const float A0 = e0*inv, A1 = e1*inv, A2 = e2*inv;
#pragma unroll
  for (int i = 0; i < 4; ++i) {
    float o = A0 * VH[k0 + i*64];
    if (ne > 1) o += A1 * VH[k1 + i*64];
    if (ne > 2) o += A2 * VH[k2 + i*64];
    OA[qoff + i*64] = o;
  }
}

// ---------------------------------------------------------------------------
// K6: O = OA @ attn_out_w^T + b  (128 gemm blocks; copy chunks [5500,6600))
// ---------------------------------------------------------------------------
__global__ __launch_bounds__(256)
void k_oproj(const float* __restrict__ x, const float* __restrict__ OA,
             const float* __restrict__ Wo, const float* __restrict__ Bo,
             float* __restrict__ O, float* __restrict__ out)
{
  const int bid = blockIdx.x;
  if (bid >= 128) { copy4(x, out, 5500 + (bid - 128) * 4); return; }
  const int j0 = bid*8 + (threadIdx.x >> 6)*2;
  float A0[28], A1[28];
#pragma unroll
  for (int r = 0; r < 28; ++r) { A0[r]=0.f; A1[r]=0.f; }
  SrcR src{OA};
  gemm_acc<28,4>(A0, A1, src, Wo, DM, 0, j0);
  gemm_fin<28>(A0, A1, Bo, j0, O, DM, 0);
}

// ---------------------------------------------------------------------------
// K7: UP = [O | x-rows] @ fus_w^T + b (K=2048; 128 blocks; chunks [6600,7600))
// ---------------------------------------------------------------------------
__global__ __launch_bounds__(256)
void k_fus(const float* __restrict__ x, const float* __restrict__ O,
           const float* __restrict__ Wf, const float* __restrict__ Bf,
           float* __restrict__ UP, float* __restrict__ out)
{
  const int bid = blockIdx.x;
  if (bid >= 128) { copy4(x, out, 6600 + (bid - 128) * 4); return; }
  const int j0 = bid*8 + (threadIdx.x >> 6)*2;
  float A0[28], A1[28];
#pragma unroll
  for (int r = 0; r < 28; ++r) { A0[r]=0.f; A1[r]=0.f; }
  SrcR srcO{O};
  gemm_acc<28,4>(A0, A1, srcO, Wf, 2048, 0, j0);
  SrcQ srcX{x};
  gemm_acc<28,4>(A0, A1, srcX, Wf, 2048, 1024, j0);
  gemm_fin<28>(A0, A1, Bf, j0, UP, DM, 0);
}

// ---------------------------------------------------------------------------
// K8: final LN + scatter the 28 rows (28 blocks; copy chunks [7600,8192))
// ---------------------------------------------------------------------------
__global__ __launch_bounds__(256)
void k_final(const float* __restrict__ x, const float* __restrict__ UP,
             const float* __restrict__ g, const float* __restrict__ bt,
             float* __restrict__ out)
{
  __shared__ float s1[4], s2[4];
  const int bid = blockIdx.x;
  if (bid >= 28) { copy4(x, out, 7600 + (bid - 28) * 4); return; }
  const int p = bid >> 2, b = bid & 3;
  const int j = threadIdx.x * 4;
  const int lane = threadIdx.x & 63, wv = threadIdx.x >> 6;
  const float4 v = *(const float4*)(UP + (size_t)bid*DM + j);
  float s = v.x+v.y+v.z+v.w;
  float q = v.x*v.x+v.y*v.y+v.z*v.z+v.w*v.w;
#pragma unroll
  for (int off = 32; off >= 1; off >>= 1) {
    s += __shfl_xor(s, off); q += __shfl_xor(q, off);
  }
  if (lane == 0) { s1[wv] = s; s2[wv] = q; }
  __syncthreads();
  const float ts = s1[0]+s1[1]+s1[2]+s1[3];
  const float tq = s2[0]+s2[1]+s2[2]+s2[3];
  const float m = ts * (1.f/1024.f);
  const float rs = rsqrtf(tq * (1.f/1024.f) - m*m + 1e-5f);
  const float* gg = g + j;
  const float* bb = bt + j;
  float4 o;
  o.x = (v.x-m)*rs*gg[0] + bb[0];
  o.y = (v.y-m)*rs*gg[1] + bb[1];
  o.z = (v.z-m)*rs*gg[2] + bb[2];
  o.w = (v.w-m)*rs*gg[3] + bb[3];
  *(float4*)(out + ((size_t)b*SEQ + c_pos[p])*DM + j) = o;
}

// ---------------------------------------------------------------------------
// Launch. Copy chunk budget (4 per copy block), total 8192:
//   lat1 1000 | ln 1200 | lat2 1000 | qkv 1000 | attn 1300 | oproj 1100
//   | fus 1000 | final 592
// ---------------------------------------------------------------------------
extern "C" void kernel_launch(void* const* d_in, const int* in_sizes, int n_in,
                              void* d_out, int out_size, void* d_ws, size_t ws_size,
                              hipStream_t stream)
{
  const float* x          = (const float*)d_in[0];
  const float* lt_w1      = (const float*)d_in[1];
  const float* lt_b1      = (const float*)d_in[2];
  const float* lt_ln_g    = (const float*)d_in[3];
  const float* lt_ln_b    = (const float*)d_in[4];
  const float* lt_w2      = (const float*)d_in[5];
  const float* lt_b2      = (const float*)d_in[6];
  const float* attn_in_w  = (const float*)d_in[7];
  const float* attn_in_b  = (const float*)d_in[8];
  const float* attn_out_w = (const float*)d_in[9];
  const float* attn_out_b = (const float*)d_in[10];
  const float* fus_w      = (const float*)d_in[11];
  const float* fus_b      = (const float*)d_in[12];
  const float* fus_ln_g   = (const float*)d_in[13];
  const float* fus_ln_b   = (const float*)d_in[14];
  float* out = (float*)d_out;
  float* ws  = (float*)d_ws;

  float* Hh = ws;                  // 64 x 1024
  float* G  = Hh + 65536;          // 64 x 1024
  float* KV = G  + 65536;          // 64 x 1024
  float* QH = KV + 65536;          // 28 x 1024 (32 alloc)
  float* KH = QH + 32768;          // 64 x 1024
  float* VH = KH + 65536;          // 64 x 1024
  float* OA = VH + 65536;          // 28 x 1024
  float* O  = OA + 32768;          // 28 x 1024
  float* UP = O  + 32768;          // 28 x 1024

  k_lat1 <<<634, 256, 0, stream>>>(x, lt_w1, lt_b1, Hh, out);
  k_ln   <<<364, 256, 0, stream>>>(x, Hh, lt_ln_g, lt_ln_b, G, out);
  k_lat2 <<<634, 256, 0, stream>>>(x, G, lt_w2, lt_b2, KV, out);
  k_qkv  <<<890, 256, 0, stream>>>(x, KV, attn_in_w, attn_in_b, QH, KH, VH, out);
  k_attn <<<353, 256, 0, stream>>>(x, QH, KH, VH, OA, out);
  k_oproj<<<403, 256, 0, stream>>>(x, OA, attn_out_w, attn_out_b, O, out);
  k_fus  <<<378, 256, 0, stream>>>(x, O, fus_w, fus_b, UP, out);
  k_final<<<176, 256, 0, stream>>>(x, UP, fus_ln_g, fus_ln_b, out);
}

// Round 8
// 100.054 us; speedup vs baseline: 5.7777x; 2.4788x over previous
//
#include <hip/hip_runtime.h>
#include <math.h>

// ---------------------------------------------------------------------------
// B=4, S=8192, D=1024, H=4, hd=256.
// Lattice positions {12,36,104,304,888,2592,7568}; 16 entries level-major
// (rows = e*4+b: L1 0..27, L2 28..51, L3 52..63).
//
// 9 kernels, stream-ordered. Surplus blocks in every kernel copy a static
// slice of x->out (plain loads keep x L3-resident; nontemporal stores;
// skip the 28 chain-written rows). All GEMMs use the round-0-proven shape:
// wave = 4 cols x 8 rows (A[4][8] = 32 regs, VGPR ~64, runtime k-loop).
// ---------------------------------------------------------------------------

#define SEQ 8192
#define DM  1024

typedef float fx4 __attribute__((ext_vector_type(4)));

__device__ __constant__ int c_nodes[16][3] = {
  {0,2,4},{2,4,12},{4,12,36},{12,36,104},{36,104,304},{104,304,888},{304,888,2592},
  {0,0,0},{0,2,0},{0,2,4},{2,4,12},{4,12,36},{12,36,104},
  {0,0,0},{0,2,0},{0,2,4}};
__device__ __constant__ float c_wt[16][3] = {
  {1,1,1},{1,1,1},{1,1,1},{1,1,1},{1,1,1},{1,1,1},{1,1,1},
  {1,0,0},{1,1,0},{1,1,1},{1,2,3},{1,2,3},{1,2,3},
  {1,0,0},{1,1,0},{1,1,1}};
__device__ __constant__ float c_winv[16] = {
  1.f/3.f,1.f/3.f,1.f/3.f,1.f/3.f,1.f/3.f,1.f/3.f,1.f/3.f,
  1.f,0.5f,1.f/3.f,1.f/6.f,1.f/6.f,1.f/6.f,
  1.f,0.5f,1.f/3.f};
__device__ __constant__ int c_pos[7]  = {12,36,104,304,888,2592,7568};
__device__ __constant__ int c_ne[7]   = {1,2,2,2,3,3,3};
__device__ __constant__ int c_posE[7][3] = {
  {0,0,0},{1,7,0},{2,8,0},{3,9,0},{4,10,13},{5,11,14},{6,12,15}};

// 8-row chunks of the 64 entry-rows (levels don't cross chunks)
__device__ __constant__ int c_lr0[9]  = {0,8,16,24,28,36,44,52,60};
__device__ __constant__ int c_lnr[9]  = {8,8,8,4,8,8,8,8,4};
__device__ __constant__ int c_llv[9]  = {0,0,0,0,1,1,1,2,2};
__device__ __constant__ int c_or0[4]  = {0,8,16,24};
__device__ __constant__ int c_onr[4]  = {8,8,8,4};

// ---------------------------------------------------------------------------
// copy 4 chunks (16 KB = 4 rows each) at c0; 16 loads in flight; stores
// skip the 28 chain-written rows.
// ---------------------------------------------------------------------------
__device__ __forceinline__ void copy4(const float* __restrict__ x,
                                      float* __restrict__ out, int c0)
{
  const fx4* __restrict__ src4 = (const fx4*)x;
  fx4* __restrict__ dst4 = (fx4*)out;
  const int tid = threadIdx.x;
  fx4 v[16]; size_t idx[16];
#pragma unroll
  for (int u = 0; u < 16; ++u) {
    const int c = c0 + (u >> 2), k = u & 3;
    idx[u] = (size_t)c * 1024 + (size_t)k * 256 + tid;
    v[u] = src4[idx[u]];
  }
#pragma unroll
  for (int u = 0; u < 16; ++u) {
    const int s = ((c0 + (u >> 2)) * 4 + (u & 3)) & (SEQ - 1);
    if (s==12 || s==36 || s==104 || s==304 || s==888 || s==2592 || s==7568)
      continue;
    __builtin_nontemporal_store(v[u], &dst4[idx[u]]);
  }
}

// ---------------------------------------------------------------------------
// GEMM core (round-0 proven shape): wave wv owns 4 cols j0..j0+3; 8 rows via
// pointer array; lanes over k (float4); runtime k-loop (no unroll blowup).
// ---------------------------------------------------------------------------
__device__ __forceinline__ void acc8(float (&A)[4][8],
                                     const float* const (&Xr)[8],
                                     const float* __restrict__ W,
                                     int Wld, int wcol, int j0, int T)
{
  const int lane = threadIdx.x & 63;
  for (int t = 0; t < T; ++t) {
    const int k = t * 256 + lane * 4;
    const float* wp = W + (size_t)j0 * Wld + wcol + k;
    const float4 w0 = *(const float4*)(wp);
    const float4 w1 = *(const float4*)(wp + Wld);
    const float4 w2 = *(const float4*)(wp + 2 * Wld);
    const float4 w3 = *(const float4*)(wp + 3 * Wld);
#pragma unroll
    for (int r = 0; r < 8; ++r) {
      const float4 xv = *(const float4*)(Xr[r] + k);
      A[0][r] += w0.x*xv.x + w0.y*xv.y + w0.z*xv.z + w0.w*xv.w;
      A[1][r] += w1.x*xv.x + w1.y*xv.y + w1.z*xv.z + w1.w*xv.w;
      A[2][r] += w2.x*xv.x + w2.y*xv.y + w2.z*xv.z + w2.w*xv.w;
      A[3][r] += w3.x*xv.x + w3.y*xv.y + w3.z*xv.z + w3.w*xv.w;
    }
  }
}

__device__ __forceinline__ void fin8(float (&A)[4][8],
                                     const float* __restrict__ Bv, int j0,
                                     float* __restrict__ Y, int ldy,
                                     int r0, int nr)
{
  const int lane = threadIdx.x & 63;
#pragma unroll
  for (int r = 0; r < 8; ++r) {
    float v0 = A[0][r], v1 = A[1][r], v2 = A[2][r], v3 = A[3][r];
#pragma unroll
    for (int off = 32; off >= 1; off >>= 1) {
      v0 += __shfl_xor(v0, off); v1 += __shfl_xor(v1, off);
      v2 += __shfl_xor(v2, off); v3 += __shfl_xor(v3, off);
    }
    if (lane == 0 && r < nr) {
      float* yr = Y + (size_t)(r0 + r) * ldy + j0;
      yr[0] = v0 + Bv[j0];     yr[1] = v1 + Bv[j0 + 1];
      yr[2] = v2 + Bv[j0 + 2]; yr[3] = v3 + Bv[j0 + 3];
    }
  }
}

// ---------------------------------------------------------------------------
// K0: F rows (64 blocks; copy chunks [0,1040))
// ---------------------------------------------------------------------------
__global__ __launch_bounds__(256)
void k_feats(const float* __restrict__ x, float* __restrict__ F,
             float* __restrict__ out)
{
  const int bid = blockIdx.x;
  if (bid >= 64) { copy4(x, out, 0 + (bid - 64) * 4); return; }
  const int e = bid >> 2, b = bid & 3;
  const int d = threadIdx.x * 4;
  float4 s = make_float4(0.f, 0.f, 0.f, 0.f);
#pragma unroll
  for (int n = 0; n < 3; ++n) {
    const float w = c_wt[e][n];
    const float4 v = *(const float4*)(x + ((size_t)b*SEQ + c_nodes[e][n])*DM + d);
    s.x += w*v.x; s.y += w*v.y; s.z += w*v.z; s.w += w*v.w;
  }
  const float inv = c_winv[e];
  s.x*=inv; s.y*=inv; s.z*=inv; s.w*=inv;
  *(float4*)(F + (size_t)bid*DM + d) = s;
}

// ---------------------------------------------------------------------------
// K1: H = F @ lt_w1^T + b1 (576 gemm blocks; copy [1040,1960))
// ---------------------------------------------------------------------------
__global__ __launch_bounds__(256)
void k_lat1(const float* __restrict__ x, const float* __restrict__ F,
            const float* __restrict__ w1, const float* __restrict__ b1,
            float* __restrict__ Hh, float* __restrict__ out)
{
  const int bid = blockIdx.x;
  if (bid >= 576) { copy4(x, out, 1040 + (bid - 576) * 4); return; }
  const int ch = bid >> 6, jt = bid & 63;
  const int r0 = c_lr0[ch], nr = c_lnr[ch], lvl = c_llv[ch];
  const int j0 = jt * 16 + (threadIdx.x >> 6) * 4;
  float A[4][8] = {};
  const float* Xr[8];
#pragma unroll
  for (int r = 0; r < 8; ++r)
    Xr[r] = F + (size_t)(r0 + ((r < nr) ? r : nr - 1)) * DM;
  acc8(A, Xr, w1 + (size_t)lvl*DM*DM, DM, 0, j0, 4);
  fin8(A, b1 + lvl*DM, j0, Hh, DM, r0, nr);
}

// ---------------------------------------------------------------------------
// K2: G = GELU(LN(H)) (64 blocks; copy [1960,3080))
// ---------------------------------------------------------------------------
__global__ __launch_bounds__(256)
void k_ln(const float* __restrict__ x, const float* __restrict__ Hh,
          const float* __restrict__ lng, const float* __restrict__ lnb,
          float* __restrict__ G, float* __restrict__ out)
{
  __shared__ float s1[4], s2[4];
  const int bid = blockIdx.x;
  if (bid >= 64) { copy4(x, out, 1960 + (bid - 64) * 4); return; }
  const int lvl = (bid < 28) ? 0 : ((bid < 52) ? 1 : 2);
  const int j = threadIdx.x * 4;
  const int lane = threadIdx.x & 63, wv = threadIdx.x >> 6;
  const float4 v = *(const float4*)(Hh + (size_t)bid*DM + j);
  float s = v.x+v.y+v.z+v.w;
  float q = v.x*v.x+v.y*v.y+v.z*v.z+v.w*v.w;
#pragma unroll
  for (int off = 32; off >= 1; off >>= 1) {
    s += __shfl_xor(s, off); q += __shfl_xor(q, off);
  }
  if (lane == 0) { s1[wv] = s; s2[wv] = q; }
  __syncthreads();
  const float ts = s1[0]+s1[1]+s1[2]+s1[3];
  const float tq = s2[0]+s2[1]+s2[2]+s2[3];
  const float m = ts * (1.f/1024.f);
  const float rs = rsqrtf(tq * (1.f/1024.f) - m*m + 1e-5f);
  const float4 g4 = *(const float4*)(lng + (size_t)lvl*DM + j);
  const float4 b4 = *(const float4*)(lnb + (size_t)lvl*DM + j);
  const float t0 = (v.x-m)*rs*g4.x + b4.x;
  const float t1 = (v.y-m)*rs*g4.y + b4.y;
  const float t2 = (v.z-m)*rs*g4.z + b4.z;
  const float t3 = (v.w-m)*rs*g4.w + b4.w;
  const float kc = 0.70710678118654752f;
  float4 o;
  o.x = 0.5f*t0*(1.f+erff(t0*kc));
  o.y = 0.5f*t1*(1.f+erff(t1*kc));
  o.z = 0.5f*t2*(1.f+erff(t2*kc));
  o.w = 0.5f*t3*(1.f+erff(t3*kc));
  *(float4*)(G + (size_t)bid*DM + j) = o;
}

// ---------------------------------------------------------------------------
// K3: KV = G @ lt_w2^T + b2 (576 gemm blocks; copy [3080,4000))
// ---------------------------------------------------------------------------
__global__ __launch_bounds__(256)
void k_lat2(const float* __restrict__ x, const float* __restrict__ G,
            const float* __restrict__ w2, const float* __restrict__ b2,
            float* __restrict__ KV, float* __restrict__ out)
{
  const int bid = blockIdx.x;
  if (bid >= 576) { copy4(x, out, 3080 + (bid - 576) * 4); return; }
  const int ch = bid >> 6, jt = bid & 63;
  const int r0 = c_lr0[ch], nr = c_lnr[ch], lvl = c_llv[ch];
  const int j0 = jt * 16 + (threadIdx.x >> 6) * 4;
  float A[4][8] = {};
  const float* Xr[8];
#pragma unroll
  for (int r = 0; r < 8; ++r)
    Xr[r] = G + (size_t)(r0 + ((r < nr) ? r : nr - 1)) * DM;
  acc8(A, Xr, w2 + (size_t)lvl*DM*DM, DM, 0, j0, 4);
  fin8(A, b2 + lvl*DM, j0, KV, DM, r0, nr);
}

// ---------------------------------------------------------------------------
// K4: Q/K/V projections (1280 gemm blocks; copy [4000,4512))
// ch 0..3: Q from x rows; 4..11: K; 12..19: V
// ---------------------------------------------------------------------------
__global__ __launch_bounds__(256)
void k_qkv(const float* __restrict__ x, const float* __restrict__ KV,
           const float* __restrict__ Wi, const float* __restrict__ Bi,
           float* __restrict__ QH, float* __restrict__ KH,
           float* __restrict__ VH, float* __restrict__ out)
{
  const int bid = blockIdx.x;
  if (bid >= 1280) { copy4(x, out, 4000 + (bid - 1280) * 4); return; }
  const int ch = bid >> 6, jt = bid & 63;
  const int j0 = jt * 16 + (threadIdx.x >> 6) * 4;
  float A[4][8] = {};
  const float* Xr[8];
  if (ch < 4) {
    const int r0 = c_or0[ch], nr = c_onr[ch];
#pragma unroll
    for (int r = 0; r < 8; ++r) {
      const int i = r0 + ((r < nr) ? r : nr - 1);
      Xr[r] = x + ((size_t)(i & 3)*SEQ + c_pos[i >> 2])*DM;
    }
    acc8(A, Xr, Wi, DM, 0, j0, 4);
    fin8(A, Bi, j0, QH, DM, r0, nr);
  } else if (ch < 12) {
    const int r0 = (ch - 4) * 8;
#pragma unroll
    for (int r = 0; r < 8; ++r) Xr[r] = KV + (size_t)(r0 + r)*DM;
    acc8(A, Xr, Wi + (size_t)DM*DM, DM, 0, j0, 4);
    fin8(A, Bi + DM, j0, KH, DM, r0, 8);
  } else {
    const int r0 = (ch - 12) * 8;
#pragma unroll
    for (int r = 0; r < 8; ++r) Xr[r] = KV + (size_t)(r0 + r)*DM;
    acc8(A, Xr, Wi + (size_t)2*DM*DM, DM, 0, j0, 4);
    fin8(A, Bi + 2*DM, j0, VH, DM, r0, 8);
  }
}

// ---------------------------------------------------------------------------
// K5: attention (28 blocks; copy [4512,5712))
// ---------------------------------------------------------------------------
__global__ __launch_bounds__(256)
void k_attn(const float* __restrict__ x, const float* __restrict__ QH,
            const float* __restrict__ KH, const float* __restrict__ VH,
            float* __restrict__ OA, float* __restrict__ out)
{
  const int bid = blockIdx.x;
  if (bid >= 28) { copy4(x, out, 4512 + (bid - 28) * 4); return; }
  const int p = bid >> 2, b = bid & 3;
  const int h = threadIdx.x >> 6, lane = threadIdx.x & 63;
  const int ne = c_ne[p];
  const int qoff = (p*4+b)*DM + h*256 + lane;
  const float q0 = QH[qoff], q1 = QH[qoff+64], q2 = QH[qoff+128], q3 = QH[qoff+192];
  float sc0 = -1e30f, sc1 = -1e30f, sc2 = -1e30f;
  int k0 = 0, k1 = 0, k2 = 0;
  {
    k0 = (c_posE[p][0]*4 + b)*DM + h*256 + lane;
    float pr = q0*KH[k0] + q1*KH[k0+64] + q2*KH[k0+128] + q3*KH[k0+192];
#pragma unroll
    for (int off = 32; off >= 1; off >>= 1) pr += __shfl_xor(pr, off);
    sc0 = pr * 0.0625f;
  }
  if (ne > 1) {
    k1 = (c_posE[p][1]*4 + b)*DM + h*256 + lane;
    float pr = q0*KH[k1] + q1*KH[k1+64] + q2*KH[k1+128] + q3*KH[k1+192];
#pragma unroll
    for (int off = 32; off >= 1; off >>= 1) pr += __shfl_xor(pr, off);
    sc1 = pr * 0.0625f;
  }
  if (ne > 2) {
    k2 = (c_posE[p][2]*4 + b)*DM + h*256 + lane;
    float pr = q0*KH[k2] + q1*KH[k2+64] + q2*KH[k2+128] + q3*KH[k2+192];
#pragma unroll
    for (int off = 32; off >= 1; off >>= 1) pr += __shfl_xor(pr, off);
    sc2 = pr * 0.0625f;
  }
  const float m = fmaxf(sc0, fmaxf(sc1, sc2));
  const float e0 = expf(sc0 - m);
  const float e1 = (ne > 1) ? expf(sc1 - m) : 0.f;
  const float e2 = (ne > 2) ? expf(sc2 - m) : 0.f;
  const float inv = 1.f / (e0 + e1 + e2);
  const float A0 = e0*inv, A1 = e1*inv, A2 = e2*inv;
#pragma unroll
  for (int i = 0; i < 4; ++i) {
    float o = A0 * VH[k0 + i*64];
    if (ne > 1) o += A1 * VH[k1 + i*64];
    if (ne > 2) o += A2 * VH[k2 + i*64];
    OA[qoff + i*64] = o;
  }
}

// ---------------------------------------------------------------------------
// K6: O = OA @ attn_out_w^T + b (256 gemm blocks; copy [5712,6712))
// ---------------------------------------------------------------------------
__global__ __launch_bounds__(256)
void k_oproj(const float* __restrict__ x, const float* __restrict__ OA,
             const float* __restrict__ Wo, const float* __restrict__ Bo,
             float* __restrict__ O, float* __restrict__ out)
{
  const int bid = blockIdx.x;
  if (bid >= 256) { copy4(x, out, 5712 + (bid - 256) * 4); return; }
  const int ch = bid >> 6, jt = bid & 63;
  const int r0 = c_or0[ch], nr = c_onr[ch];
  const int j0 = jt * 16 + (threadIdx.x >> 6) * 4;
  float A[4][8] = {};
  const float* Xr[8];
#pragma unroll
  for (int r = 0; r < 8; ++r)
    Xr[r] = OA + (size_t)(r0 + ((r < nr) ? r : nr - 1)) * DM;
  acc8(A, Xr, Wo, DM, 0, j0, 4);
  fin8(A, Bo, j0, O, DM, r0, nr);
}

// ---------------------------------------------------------------------------
// K7: UP = [O | x-rows] @ fus_w^T + b (K=2048; 256 blocks; copy [6712,7712))
// ---------------------------------------------------------------------------
__global__ __launch_bounds__(256)
void k_fus(const float* __restrict__ x, const float* __restrict__ O,
           const float* __restrict__ Wf, const float* __restrict__ Bf,
           float* __restrict__ UP, float* __restrict__ out)
{
  const int bid = blockIdx.x;
  if (bid >= 256) { copy4(x, out, 6712 + (bid - 256) * 4); return; }
  const int ch = bid >> 6, jt = bid & 63;
  const int r0 = c_or0[ch], nr = c_onr[ch];
  const int j0 = jt * 16 + (threadIdx.x >> 6) * 4;
  float A[4][8] = {};
  const float* XrO[8]; const float* XrX[8];
#pragma unroll
  for (int r = 0; r < 8; ++r) {
    const int i = r0 + ((r < nr) ? r : nr - 1);
    XrO[r] = O + (size_t)i*DM;
    XrX[r] = x + ((size_t)(i & 3)*SEQ + c_pos[i >> 2])*DM;
  }
  acc8(A, XrO, Wf, 2048, 0, j0, 4);
  acc8(A, XrX, Wf, 2048, 1024, j0, 4);
  fin8(A, Bf, j0, UP, DM, r0, nr);
}

// ---------------------------------------------------------------------------
// K8: final LN + scatter (28 blocks; copy [7712,8192))
// ---------------------------------------------------------------------------
__global__ __launch_bounds__(256)
void k_final(const float* __restrict__ x, const float* __restrict__ UP,
             const float* __restrict__ g, const float* __restrict__ bt,
             float* __restrict__ out)
{
  __shared__ float s1[4], s2[4];
  const int bid = blockIdx.x;
  if (bid >= 28) { copy4(x, out, 7712 + (bid - 28) * 4); return; }
  const int p = bid >> 2, b = bid & 3;
  const int j = threadIdx.x * 4;
  const int lane = threadIdx.x & 63, wv = threadIdx.x >> 6;
  const float4 v = *(const float4*)(UP + (size_t)bid*DM + j);
  float s = v.x+v.y+v.z+v.w;
  float q = v.x*v.x+v.y*v.y+v.z*v.z+v.w*v.w;
#pragma unroll
  for (int off = 32; off >= 1; off >>= 1) {
    s += __shfl_xor(s, off); q += __shfl_xor(q, off);
  }
  if (lane == 0) { s1[wv] = s; s2[wv] = q; }
  __syncthreads();
  const float ts = s1[0]+s1[1]+s1[2]+s1[3];
  const float tq = s2[0]+s2[1]+s2[2]+s2[3];
  const float m = ts * (1.f/1024.f);
  const float rs = rsqrtf(tq * (1.f/1024.f) - m*m + 1e-5f);
  const float* gg = g + j;
  const float* bb = bt + j;
  float4 o;
  o.x = (v.x-m)*rs*gg[0] + bb[0];
  o.y = (v.y-m)*rs*gg[1] + bb[1];
  o.z = (v.z-m)*rs*gg[2] + bb[2];
  o.w = (v.w-m)*rs*gg[3] + bb[3];
  *(float4*)(out + ((size_t)b*SEQ + c_pos[p])*DM + j) = o;
}

// ---------------------------------------------------------------------------
// Launch. Copy blocks (4 chunks each), total 2048 blocks = 8192 chunks:
//   feats 260 | lat1 230 | ln 280 | lat2 230 | qkv 128 | attn 300
//   | oproj 250 | fus 250 | final 120
// ---------------------------------------------------------------------------
extern "C" void kernel_launch(void* const* d_in, const int* in_sizes, int n_in,
                              void* d_out, int out_size, void* d_ws, size_t ws_size,
                              hipStream_t stream)
{
  const float* x          = (const float*)d_in[0];
  const float* lt_w1      = (const float*)d_in[1];
  const float* lt_b1      = (const float*)d_in[2];
  const float* lt_ln_g    = (const float*)d_in[3];
  const float* lt_ln_b    = (const float*)d_in[4];
  const float* lt_w2      = (const float*)d_in[5];
  const float* lt_b2      = (const float*)d_in[6];
  const float* attn_in_w  = (const float*)d_in[7];
  const float* attn_in_b  = (const float*)d_in[8];
  const float* attn_out_w = (const float*)d_in[9];
  const float* attn_out_b = (const float*)d_in[10];
  const float* fus_w      = (const float*)d_in[11];
  const float* fus_b      = (const float*)d_in[12];
  const float* fus_ln_g   = (const float*)d_in[13];
  const float* fus_ln_b   = (const float*)d_in[14];
  float* out = (float*)d_out;
  float* ws  = (float*)d_ws;

  float* F  = ws;                  // 64 x 1024
  float* Hh = F  + 65536;          // 64 x 1024
  float* G  = Hh + 65536;          // 64 x 1024
  float* KV = G  + 65536;          // 64 x 1024
  float* QH = KV + 65536;          // 28 x 1024 (32 alloc)
  float* KH = QH + 32768;          // 64 x 1024
  float* VH = KH + 65536;          // 64 x 1024
  float* OA = VH + 65536;          // 28 x 1024
  float* O  = OA + 32768;          // 28 x 1024
  float* UP = O  + 32768;          // 28 x 1024

  k_feats<<<324,  256, 0, stream>>>(x, F, out);
  k_lat1 <<<806,  256, 0, stream>>>(x, F, lt_w1, lt_b1, Hh, out);
  k_ln   <<<344,  256, 0, stream>>>(x, Hh, lt_ln_g, lt_ln_b, G, out);
  k_lat2 <<<806,  256, 0, stream>>>(x, G, lt_w2, lt_b2, KV, out);
  k_qkv  <<<1408, 256, 0, stream>>>(x, KV, attn_in_w, attn_in_b, QH, KH, VH, out);
  k_attn <<<328,  256, 0, stream>>>(x, QH, KH, VH, OA, out);
  k_oproj<<<506,  256, 0, stream>>>(x, OA, attn_out_w, attn_out_b, O, out);
  k_fus  <<<506,  256, 0, stream>>>(x, O, fus_w, fus_b, UP, out);
  k_final<<<148,  256, 0, stream>>>(x, UP, fus_ln_g, fus_ln_b, out);
}